// Round 1
// baseline (1215.218 us; speedup 1.0000x reference)
//
#include <hip/hip_runtime.h>
#include <math.h>

#define N_NODES 100000
#define N_EDGES 1000000
#define IN_DIM  128
#define OUT_DIM 64
#define NEG     0.2f

// ---------- helpers: monotonic float<->uint map for atomicMax on floats ----
__device__ __forceinline__ unsigned fmap(float f) {
    unsigned u = __float_as_uint(f);
    return (u >> 31) ? ~u : (u | 0x80000000u);
}
__device__ __forceinline__ float funmap(unsigned m) {
    return (m & 0x80000000u) ? __uint_as_float(m & 0x7FFFFFFFu)
                             : __uint_as_float(~m);
}

// ---------------------------------------------------------------------------
// K1: Wh = h @ W^T + b   [N,64], plus per-node scores s_src = Wh.a1, s_tgt = Wh.a2
// Block = 256 threads (4 waves), 32 nodes/block. W^T staged in LDS with XOR
// column swizzle (conflict-free transpose-write AND compute-read). h tile in
// LDS; lane d owns output dim d, 8 nodes per wave.
// ---------------------------------------------------------------------------
__global__ __launch_bounds__(256) void k1_gemm(
    const float* __restrict__ h, const float* __restrict__ W,
    const float* __restrict__ Wb, const float* __restrict__ aw,
    float* __restrict__ Wh, float* __restrict__ s_src, float* __restrict__ s_tgt)
{
    __shared__ float wt[IN_DIM * OUT_DIM];   // wt[k*64 | (d ^ (k&63))] = W[d][k]
    __shared__ float ht[32 * IN_DIM];        // 32 node rows

    const int tid = threadIdx.x;

    // stage W transposed+swizzled: coalesced global read, conflict-free LDS write
    for (int i = tid; i < IN_DIM * OUT_DIM; i += 256) {
        int d = i >> 7, k = i & 127;
        wt[(k << 6) | (d ^ (k & 63))] = W[i];
    }
    // stage 32 h rows (float4 coalesced)
    const int nbase = blockIdx.x * 32;
    {
        const float4* hs = (const float4*)(h + (size_t)nbase * IN_DIM);
        float4* hd = (float4*)ht;
        for (int i = tid; i < (32 * IN_DIM) / 4; i += 256) hd[i] = hs[i];
    }
    __syncthreads();

    const int wave = tid >> 6, lane = tid & 63;
    const int nw = wave * 8;                 // this wave's first local node

    float acc[8];
#pragma unroll
    for (int j = 0; j < 8; j++) acc[j] = 0.f;

#pragma unroll
    for (int k = 0; k < IN_DIM; k += 2) {
        float w0 = wt[(k << 6) | (lane ^ (k & 63))];
        float w1 = wt[((k + 1) << 6) | (lane ^ ((k + 1) & 63))];
#pragma unroll
        for (int j = 0; j < 8; j++) {
            float2 hv = *(const float2*)&ht[(nw + j) * IN_DIM + k];  // broadcast
            acc[j] += hv.x * w0 + hv.y * w1;
        }
    }

    const float bd = Wb[lane];
    const float a1 = aw[lane], a2 = aw[OUT_DIM + lane];
#pragma unroll
    for (int j = 0; j < 8; j++) {
        float v = acc[j] + bd;
        int n = nbase + nw + j;
        Wh[(size_t)n * OUT_DIM + lane] = v;
        float p1 = v * a1, p2 = v * a2;
#pragma unroll
        for (int off = 32; off; off >>= 1) {
            p1 += __shfl_xor(p1, off);
            p2 += __shfl_xor(p2, off);
        }
        if (lane == 0) { s_src[n] = p1; s_tgt[n] = p2; }
    }
}

// ---------------------------------------------------------------------------
// K2: logits[e] = leaky(s_src[src]+s_tgt[tgt]+ab); global max via atomicMax
// ---------------------------------------------------------------------------
__global__ __launch_bounds__(256) void k2_logits(
    const int* __restrict__ ei, const float* __restrict__ s_src,
    const float* __restrict__ s_tgt, const float* __restrict__ ab,
    float* __restrict__ logits, unsigned* __restrict__ gmax)
{
    const float ab0 = ab[0];
    float lmax = -INFINITY;
    const int stride = gridDim.x * blockDim.x;
    for (int e = blockIdx.x * blockDim.x + threadIdx.x; e < N_EDGES; e += stride) {
        int s = ei[e], t = ei[N_EDGES + e];
        float x = s_src[s] + s_tgt[t] + ab0;
        float l = x > 0.f ? x : NEG * x;
        logits[e] = l;
        lmax = fmaxf(lmax, l);
    }
#pragma unroll
    for (int off = 32; off; off >>= 1) lmax = fmaxf(lmax, __shfl_xor(lmax, off));
    __shared__ float smax[4];
    if ((threadIdx.x & 63) == 0) smax[threadIdx.x >> 6] = lmax;
    __syncthreads();
    if (threadIdx.x == 0) {
        float m = fmaxf(fmaxf(smax[0], smax[1]), fmaxf(smax[2], smax[3]));
        atomicMax(gmax, fmap(m));
    }
}

// ---------------------------------------------------------------------------
// K3: ex[e] = exp(logit - max) (in place); global sum via block-partial atomics
// ---------------------------------------------------------------------------
__global__ __launch_bounds__(256) void k3_exp(
    float* __restrict__ logits, const unsigned* __restrict__ gmax,
    float* __restrict__ gsum)
{
    const float m = funmap(*gmax);
    float lsum = 0.f;
    const int stride = gridDim.x * blockDim.x;
    for (int e = blockIdx.x * blockDim.x + threadIdx.x; e < N_EDGES; e += stride) {
        float ex = __expf(logits[e] - m);
        logits[e] = ex;
        lsum += ex;
    }
#pragma unroll
    for (int off = 32; off; off >>= 1) lsum += __shfl_xor(lsum, off);
    __shared__ float ssum[4];
    if ((threadIdx.x & 63) == 0) ssum[threadIdx.x >> 6] = lsum;
    __syncthreads();
    if (threadIdx.x == 0)
        atomicAdd(gsum, ssum[0] + ssum[1] + ssum[2] + ssum[3]);
}

// ---------------------------------------------------------------------------
// K4: scatter — wave per edge, lane = dim. Coalesced 256B gather of Wh[src],
// coalesced 256B atomicAdd into out[tgt].
// ---------------------------------------------------------------------------
__global__ __launch_bounds__(256) void k4_scatter(
    const int* __restrict__ ei, const float* __restrict__ ex,
    const float* __restrict__ gsum, const float* __restrict__ Wh,
    float* __restrict__ out)
{
    const float inv = 1.0f / gsum[0];
    const int lane = threadIdx.x & 63;
    int wid = (blockIdx.x * blockDim.x + threadIdx.x) >> 6;
    wid = __builtin_amdgcn_readfirstlane(wid);
    const int nwaves = (gridDim.x * blockDim.x) >> 6;
    for (int e = wid; e < N_EDGES; e += nwaves) {
        int s = ei[e], t = ei[N_EDGES + e];
        float a = ex[e] * inv;
        float v = a * Wh[(size_t)s * OUT_DIM + lane];
        atomicAdd(out + (size_t)t * OUT_DIM + lane, v);
    }
}

// ---------------------------------------------------------------------------
// K5: leaky relu in place on out
// ---------------------------------------------------------------------------
__global__ __launch_bounds__(256) void k5_leaky(float* __restrict__ out, int n4)
{
    const int stride = gridDim.x * blockDim.x;
    float4* o = (float4*)out;
    for (int i = blockIdx.x * blockDim.x + threadIdx.x; i < n4; i += stride) {
        float4 v = o[i];
        v.x = v.x > 0.f ? v.x : NEG * v.x;
        v.y = v.y > 0.f ? v.y : NEG * v.y;
        v.z = v.z > 0.f ? v.z : NEG * v.z;
        v.w = v.w > 0.f ? v.w : NEG * v.w;
        o[i] = v;
    }
}

extern "C" void kernel_launch(void* const* d_in, const int* in_sizes, int n_in,
                              void* d_out, int out_size, void* d_ws, size_t ws_size,
                              hipStream_t stream)
{
    const float* h  = (const float*)d_in[0];
    const float* W  = (const float*)d_in[1];
    const float* Wb = (const float*)d_in[2];
    const float* aw = (const float*)d_in[3];
    const float* ab = (const float*)d_in[4];
    const int*   ei = (const int*)d_in[5];

    // ws layout (floats): Wh[N*64] | s_src[N] | s_tgt[N] | logits/ex[E] | {u32 max, f32 sum}
    float* ws    = (float*)d_ws;
    float* Wh    = ws;
    float* s_src = Wh + (size_t)N_NODES * OUT_DIM;
    float* s_tgt = s_src + N_NODES;
    float* lg    = s_tgt + N_NODES;
    unsigned* gmax = (unsigned*)(lg + N_EDGES);
    float*    gsum = (float*)(gmax + 1);

    float* out = (float*)d_out;

    hipMemsetAsync(out, 0, (size_t)out_size * sizeof(float), stream);
    hipMemsetAsync((void*)gmax, 0, 8, stream);  // mapped-uint 0 == -inf sentinel; sum = 0

    k1_gemm<<<N_NODES / 32, 256, 0, stream>>>(h, W, Wb, aw, Wh, s_src, s_tgt);
    k2_logits<<<1024, 256, 0, stream>>>(ei, s_src, s_tgt, ab, lg, gmax);
    k3_exp<<<1024, 256, 0, stream>>>(lg, gmax, gsum);
    k4_scatter<<<4096, 256, 0, stream>>>(ei, lg, gsum, Wh, out);
    k5_leaky<<<2048, 256, 0, stream>>>(out, out_size / 4);
}

// Round 2
// 413.783 us; speedup vs baseline: 2.9369x; 2.9369x over previous
//
#include <hip/hip_runtime.h>
#include <math.h>

#define N_NODES 100000
#define N_EDGES 1000000
#define IN_DIM  128
#define OUT_DIM 64
#define NEG     0.2f

// ---------- helpers: monotonic float<->uint map for atomicMax on floats ----
__device__ __forceinline__ unsigned fmap(float f) {
    unsigned u = __float_as_uint(f);
    return (u >> 31) ? ~u : (u | 0x80000000u);
}
__device__ __forceinline__ float funmap(unsigned m) {
    return (m & 0x80000000u) ? __uint_as_float(m & 0x7FFFFFFFu)
                             : __uint_as_float(~m);
}

// ---------------------------------------------------------------------------
// K1: Wh = h @ W^T + b   [N,64], plus s_src = Wh.a1, s_tgt = Wh.a2 per node.
// Block = 256 (4 waves), 32 nodes/block. All-float4 LDS:
//   wt4[k4][d]  — lane d reads stride-1 b128 (conflict-free canonical)
//   ht4[n][k4]  — wave-uniform broadcast read (free)
// Outer k4 loop NOT unrolled + launch_bounds(256,2): no spill (R1 had VGPR=256
// and 2.7 GB of scratch traffic from the fully-unrolled float2 version).
// ---------------------------------------------------------------------------
__global__ __launch_bounds__(256, 2) void k1_gemm(
    const float* __restrict__ h, const float* __restrict__ W,
    const float* __restrict__ Wb, const float* __restrict__ aw,
    float* __restrict__ Wh, float* __restrict__ s_src, float* __restrict__ s_tgt)
{
    __shared__ float4 wt4[32][64];   // 32 KB: wt4[k4][d] = W[d][4k4..4k4+3]
    __shared__ float4 ht4[32][32];   // 16 KB: ht4[n][k4]

    const int tid = threadIdx.x;

    // stage W (coalesced global float4 read; LDS write conflicts once, negligible)
    const float4* W4 = (const float4*)W;
    for (int i = tid; i < 64 * 32; i += 256)
        wt4[i & 31][i >> 5] = W4[i];

    // stage 32 h rows (flat copy, coalesced)
    const int nbase = blockIdx.x * 32;
    {
        const float4* hs = (const float4*)(h + (size_t)nbase * IN_DIM);
        float4* hd = &ht4[0][0];
        for (int i = tid; i < 32 * 32; i += 256) hd[i] = hs[i];
    }
    __syncthreads();

    const int wave = tid >> 6, lane = tid & 63;
    const int nw = wave * 8;                 // this wave's first local node

    float acc[8];
#pragma unroll
    for (int j = 0; j < 8; j++) acc[j] = 0.f;

    for (int k4 = 0; k4 < 32; ++k4) {
        float4 wv = wt4[k4][lane];
#pragma unroll
        for (int j = 0; j < 8; j++) {
            float4 hv = ht4[nw + j][k4];     // broadcast
            acc[j] += wv.x * hv.x + wv.y * hv.y + wv.z * hv.z + wv.w * hv.w;
        }
    }

    const float bd = Wb[lane];
    const float a1 = aw[lane], a2 = aw[OUT_DIM + lane];
#pragma unroll
    for (int j = 0; j < 8; j++) {
        float v = acc[j] + bd;
        int n = nbase + nw + j;
        Wh[(size_t)n * OUT_DIM + lane] = v;
        float p1 = v * a1, p2 = v * a2;
#pragma unroll
        for (int off = 32; off; off >>= 1) {
            p1 += __shfl_xor(p1, off);
            p2 += __shfl_xor(p2, off);
        }
        if (lane == 0) { s_src[n] = p1; s_tgt[n] = p2; }
    }
}

// ---------------------------------------------------------------------------
// K2: logits[e] = leaky(s_src[src]+s_tgt[tgt]+ab); global max via atomicMax
// ---------------------------------------------------------------------------
__global__ __launch_bounds__(256) void k2_logits(
    const int* __restrict__ ei, const float* __restrict__ s_src,
    const float* __restrict__ s_tgt, const float* __restrict__ ab,
    float* __restrict__ logits, unsigned* __restrict__ gmax)
{
    const float ab0 = ab[0];
    float lmax = -INFINITY;
    const int stride = gridDim.x * blockDim.x;
    for (int e = blockIdx.x * blockDim.x + threadIdx.x; e < N_EDGES; e += stride) {
        int s = ei[e], t = ei[N_EDGES + e];
        float x = s_src[s] + s_tgt[t] + ab0;
        float l = x > 0.f ? x : NEG * x;
        logits[e] = l;
        lmax = fmaxf(lmax, l);
    }
#pragma unroll
    for (int off = 32; off; off >>= 1) lmax = fmaxf(lmax, __shfl_xor(lmax, off));
    __shared__ float smax[4];
    if ((threadIdx.x & 63) == 0) smax[threadIdx.x >> 6] = lmax;
    __syncthreads();
    if (threadIdx.x == 0) {
        float m = fmaxf(fmaxf(smax[0], smax[1]), fmaxf(smax[2], smax[3]));
        atomicMax(gmax, fmap(m));
    }
}

// ---------------------------------------------------------------------------
// K3: ex[e] = exp(logit - max) (in place); global sum via block-partial atomics
// ---------------------------------------------------------------------------
__global__ __launch_bounds__(256) void k3_exp(
    float* __restrict__ logits, const unsigned* __restrict__ gmax,
    float* __restrict__ gsum)
{
    const float m = funmap(*gmax);
    float lsum = 0.f;
    const int stride = gridDim.x * blockDim.x;
    for (int e = blockIdx.x * blockDim.x + threadIdx.x; e < N_EDGES; e += stride) {
        float ex = __expf(logits[e] - m);
        logits[e] = ex;
        lsum += ex;
    }
#pragma unroll
    for (int off = 32; off; off >>= 1) lsum += __shfl_xor(lsum, off);
    __shared__ float ssum[4];
    if ((threadIdx.x & 63) == 0) ssum[threadIdx.x >> 6] = lsum;
    __syncthreads();
    if (threadIdx.x == 0)
        atomicAdd(gsum, ssum[0] + ssum[1] + ssum[2] + ssum[3]);
}

// ---------------------------------------------------------------------------
// K4: scatter — wave per edge, lane = dim. Coalesced 256B gather of Wh[src],
// coalesced 256B atomicAdd into out[tgt].
// ---------------------------------------------------------------------------
__global__ __launch_bounds__(256) void k4_scatter(
    const int* __restrict__ ei, const float* __restrict__ ex,
    const float* __restrict__ gsum, const float* __restrict__ Wh,
    float* __restrict__ out)
{
    const float inv = 1.0f / gsum[0];
    const int lane = threadIdx.x & 63;
    int wid = (blockIdx.x * blockDim.x + threadIdx.x) >> 6;
    wid = __builtin_amdgcn_readfirstlane(wid);
    const int nwaves = (gridDim.x * blockDim.x) >> 6;
    for (int e = wid; e < N_EDGES; e += nwaves) {
        int s = ei[e], t = ei[N_EDGES + e];
        float a = ex[e] * inv;
        float v = a * Wh[(size_t)s * OUT_DIM + lane];
        atomicAdd(out + (size_t)t * OUT_DIM + lane, v);
    }
}

// ---------------------------------------------------------------------------
// K5: leaky relu in place on out
// ---------------------------------------------------------------------------
__global__ __launch_bounds__(256) void k5_leaky(float* __restrict__ out, int n4)
{
    const int stride = gridDim.x * blockDim.x;
    float4* o = (float4*)out;
    for (int i = blockIdx.x * blockDim.x + threadIdx.x; i < n4; i += stride) {
        float4 v = o[i];
        v.x = v.x > 0.f ? v.x : NEG * v.x;
        v.y = v.y > 0.f ? v.y : NEG * v.y;
        v.z = v.z > 0.f ? v.z : NEG * v.z;
        v.w = v.w > 0.f ? v.w : NEG * v.w;
        o[i] = v;
    }
}

extern "C" void kernel_launch(void* const* d_in, const int* in_sizes, int n_in,
                              void* d_out, int out_size, void* d_ws, size_t ws_size,
                              hipStream_t stream)
{
    const float* h  = (const float*)d_in[0];
    const float* W  = (const float*)d_in[1];
    const float* Wb = (const float*)d_in[2];
    const float* aw = (const float*)d_in[3];
    const float* ab = (const float*)d_in[4];
    const int*   ei = (const int*)d_in[5];

    // ws layout (floats): Wh[N*64] | s_src[N] | s_tgt[N] | logits/ex[E] | {u32 max, f32 sum}
    float* ws    = (float*)d_ws;
    float* Wh    = ws;
    float* s_src = Wh + (size_t)N_NODES * OUT_DIM;
    float* s_tgt = s_src + N_NODES;
    float* lg    = s_tgt + N_NODES;
    unsigned* gmax = (unsigned*)(lg + N_EDGES);
    float*    gsum = (float*)(gmax + 1);

    float* out = (float*)d_out;

    hipMemsetAsync(out, 0, (size_t)out_size * sizeof(float), stream);
    hipMemsetAsync((void*)gmax, 0, 8, stream);  // mapped-uint 0 == -inf sentinel; sum = 0

    k1_gemm<<<N_NODES / 32, 256, 0, stream>>>(h, W, Wb, aw, Wh, s_src, s_tgt);
    k2_logits<<<1024, 256, 0, stream>>>(ei, s_src, s_tgt, ab, lg, gmax);
    k3_exp<<<1024, 256, 0, stream>>>(lg, gmax, gsum);
    k4_scatter<<<4096, 256, 0, stream>>>(ei, lg, gsum, Wh, out);
    k5_leaky<<<2048, 256, 0, stream>>>(out, out_size / 4);
}

// Round 3
// 336.206 us; speedup vs baseline: 3.6145x; 1.2307x over previous
//
#include <hip/hip_runtime.h>
#include <math.h>

#define N_NODES 100000
#define N_EDGES 1000000
#define IN_DIM  128
#define OUT_DIM 64
#define NEG     0.2f

#define SCAN_BLOCKS 391   // ceil(100000/256)

// ---------- helpers: monotonic float<->uint map for atomicMax on floats ----
__device__ __forceinline__ unsigned fmap(float f) {
    unsigned u = __float_as_uint(f);
    return (u >> 31) ? ~u : (u | 0x80000000u);
}
__device__ __forceinline__ float funmap(unsigned m) {
    return (m & 0x80000000u) ? __uint_as_float(m & 0x7FFFFFFFu)
                             : __uint_as_float(~m);
}

// ---------------------------------------------------------------------------
// K1: Wh = h @ W^T + b, plus s_src = Wh.a1, s_tgt = Wh.a2.
// Lane = out-dim d. W^T in LDS (1 stride-1 ds_read_b128 per iter). h read with
// wave-uniform addresses (readfirstlane'd node) -> scalar/broadcast loads, no
// LDS h tile (R2 was DS-pipe bound: 9 b128/iter, 8 of them zero-reuse
// broadcasts). unroll 2 to avoid the R1 full-unroll spill.
// ---------------------------------------------------------------------------
__global__ __launch_bounds__(256, 2) void k1_gemm(
    const float* __restrict__ h, const float* __restrict__ W,
    const float* __restrict__ Wb, const float* __restrict__ aw,
    float* __restrict__ Wh, float* __restrict__ s_src, float* __restrict__ s_tgt)
{
    __shared__ float4 wt4[32][64];   // wt4[k4][d] = W[d][4k4..4k4+3]

    const int tid = threadIdx.x;
    const int lane = tid & 63, wave = tid >> 6;

    // stage W: lane = d -> stride-1 conflict-free LDS writes. Global side is
    // strided 16B reads of a 32KB array (L2-absorbed after first blocks).
    {
        const float4* W4 = (const float4*)W;
        const int d = tid & 63, k4hi = tid >> 6;   // k4hi in 0..3
#pragma unroll
        for (int it = 0; it < 8; ++it) {
            int k4 = (it << 2) | k4hi;
            wt4[k4][d] = W4[d * 32 + k4];
        }
    }
    __syncthreads();

    const int n0 = __builtin_amdgcn_readfirstlane(blockIdx.x * 32 + wave * 8);
    const float4* __restrict__ h4 = (const float4*)h;

    float acc[8];
#pragma unroll
    for (int j = 0; j < 8; j++) acc[j] = 0.f;

#pragma unroll 2
    for (int k4 = 0; k4 < 32; ++k4) {
        float4 wv = wt4[k4][lane];
#pragma unroll
        for (int j = 0; j < 8; j++) {
            float4 hv = h4[(size_t)(n0 + j) * 32 + k4];   // wave-uniform addr
            acc[j] += wv.x * hv.x + wv.y * hv.y + wv.z * hv.z + wv.w * hv.w;
        }
    }

    const float bd = Wb[lane];
    const float a1 = aw[lane], a2 = aw[OUT_DIM + lane];
#pragma unroll
    for (int j = 0; j < 8; j++) {
        float v = acc[j] + bd;
        int n = n0 + j;
        Wh[(size_t)n * OUT_DIM + lane] = v;
        float p1 = v * a1, p2 = v * a2;
#pragma unroll
        for (int off = 32; off; off >>= 1) {
            p1 += __shfl_xor(p1, off);
            p2 += __shfl_xor(p2, off);
        }
        if (lane == 0) { s_src[n] = p1; s_tgt[n] = p2; }
    }
}

// ---------------------------------------------------------------------------
// K2: global max of leaky(s_src[src]+s_tgt[tgt]+ab) + degree histogram of tgt.
// Logits NOT materialized (recomputed in k3 from L2-resident s arrays).
// ---------------------------------------------------------------------------
__global__ __launch_bounds__(256) void k2_maxhist(
    const int* __restrict__ ei, const float* __restrict__ s_src,
    const float* __restrict__ s_tgt, const float* __restrict__ ab,
    unsigned* __restrict__ deg, unsigned* __restrict__ gmax)
{
    const float ab0 = ab[0];
    float lmax = -INFINITY;
    const int stride = gridDim.x * blockDim.x;
    for (int e = blockIdx.x * blockDim.x + threadIdx.x; e < N_EDGES; e += stride) {
        int s = ei[e], t = ei[N_EDGES + e];
        float x = s_src[s] + s_tgt[t] + ab0;
        float l = x > 0.f ? x : NEG * x;
        lmax = fmaxf(lmax, l);
        atomicAdd(&deg[t], 1u);
    }
#pragma unroll
    for (int off = 32; off; off >>= 1) lmax = fmaxf(lmax, __shfl_xor(lmax, off));
    __shared__ float smax[4];
    if ((threadIdx.x & 63) == 0) smax[threadIdx.x >> 6] = lmax;
    __syncthreads();
    if (threadIdx.x == 0) {
        float m = fmaxf(fmaxf(smax[0], smax[1]), fmaxf(smax[2], smax[3]));
        atomicMax(gmax, fmap(m));
    }
}

// ---------------------------------------------------------------------------
// Scan (3 kernels): exclusive prefix sum of deg[100000] -> row[], cursor[]
// ---------------------------------------------------------------------------
__global__ __launch_bounds__(256) void k_scan1(
    const unsigned* __restrict__ deg, unsigned* __restrict__ psum)
{
    const int i = blockIdx.x * 256 + threadIdx.x;
    unsigned v = (i < N_NODES) ? deg[i] : 0u;
    unsigned w = v;
#pragma unroll
    for (int off = 32; off; off >>= 1) w += __shfl_xor(w, off);
    __shared__ unsigned ss[4];
    if ((threadIdx.x & 63) == 0) ss[threadIdx.x >> 6] = w;
    __syncthreads();
    if (threadIdx.x == 0) psum[blockIdx.x] = ss[0] + ss[1] + ss[2] + ss[3];
}

__global__ __launch_bounds__(512) void k_scan2(
    const unsigned* __restrict__ psum, unsigned* __restrict__ poff)
{
    __shared__ unsigned sc[512];
    const int t = threadIdx.x;
    unsigned v = (t < SCAN_BLOCKS) ? psum[t] : 0u;
    sc[t] = v;
    __syncthreads();
    for (int off = 1; off < 512; off <<= 1) {
        unsigned u = (t >= off) ? sc[t - off] : 0u;
        __syncthreads();
        sc[t] += u;
        __syncthreads();
    }
    if (t < SCAN_BLOCKS) poff[t] = sc[t] - v;   // exclusive
}

__global__ __launch_bounds__(256) void k_scan3(
    const unsigned* __restrict__ deg, const unsigned* __restrict__ poff,
    unsigned* __restrict__ row, unsigned* __restrict__ cursor)
{
    __shared__ unsigned sc[256];
    const int t = threadIdx.x;
    const int i = blockIdx.x * 256 + t;
    unsigned v = (i < N_NODES) ? deg[i] : 0u;
    sc[t] = v;
    __syncthreads();
    for (int off = 1; off < 256; off <<= 1) {
        unsigned u = (t >= off) ? sc[t - off] : 0u;
        __syncthreads();
        sc[t] += u;
        __syncthreads();
    }
    unsigned r = poff[blockIdx.x] + sc[t] - v;   // exclusive
    if (i < N_NODES) { row[i] = r; cursor[i] = r; }
    if (i == 0) row[N_NODES] = N_EDGES;
}

// ---------------------------------------------------------------------------
// K3: ex = exp(leaky(logit) - max); global sum; scatter (src, ex) into bins.
// ---------------------------------------------------------------------------
__global__ __launch_bounds__(256) void k3_expfill(
    const int* __restrict__ ei, const float* __restrict__ s_src,
    const float* __restrict__ s_tgt, const float* __restrict__ ab,
    const unsigned* __restrict__ gmax, float* __restrict__ gsum,
    unsigned* __restrict__ cursor, int* __restrict__ bin_src,
    float* __restrict__ bin_a)
{
    const float m = funmap(*gmax);
    const float ab0 = ab[0];
    float lsum = 0.f;
    const int stride = gridDim.x * blockDim.x;
    for (int e = blockIdx.x * blockDim.x + threadIdx.x; e < N_EDGES; e += stride) {
        int s = ei[e], t = ei[N_EDGES + e];
        float x = s_src[s] + s_tgt[t] + ab0;
        float l = x > 0.f ? x : NEG * x;
        float ex = __expf(l - m);
        lsum += ex;
        unsigned pos = atomicAdd(&cursor[t], 1u);
        bin_src[pos] = s;
        bin_a[pos] = ex;
    }
#pragma unroll
    for (int off = 32; off; off >>= 1) lsum += __shfl_xor(lsum, off);
    __shared__ float ssum[4];
    if ((threadIdx.x & 63) == 0) ssum[threadIdx.x >> 6] = lsum;
    __syncthreads();
    if (threadIdx.x == 0)
        atomicAdd(gsum, ssum[0] + ssum[1] + ssum[2] + ssum[3]);
}

// ---------------------------------------------------------------------------
// K4: gather — wave per tgt node, lane = dim. Wave-uniform (src, ex) loads,
// coalesced 256B Wh[src] gathers, ONE plain store per node, leaky fused.
// No atomics on out.
// ---------------------------------------------------------------------------
__global__ __launch_bounds__(256) void k_gather(
    const unsigned* __restrict__ row, const int* __restrict__ bin_src,
    const float* __restrict__ bin_a, const float* __restrict__ gsum,
    const float* __restrict__ Wh, float* __restrict__ out)
{
    const int lane = threadIdx.x & 63;
    const int t = __builtin_amdgcn_readfirstlane(blockIdx.x * 4 + (threadIdx.x >> 6));
    if (t >= N_NODES) return;
    const int beg = __builtin_amdgcn_readfirstlane((int)row[t]);
    const int end = __builtin_amdgcn_readfirstlane((int)row[t + 1]);
    float acc = 0.f;
    for (int j = beg; j < end; ++j) {
        int s = bin_src[j];            // wave-uniform
        float a = bin_a[j];            // wave-uniform
        acc += a * Wh[(size_t)s * OUT_DIM + lane];
    }
    float v = acc * (1.0f / gsum[0]);
    out[(size_t)t * OUT_DIM + lane] = v > 0.f ? v : NEG * v;
}

extern "C" void kernel_launch(void* const* d_in, const int* in_sizes, int n_in,
                              void* d_out, int out_size, void* d_ws, size_t ws_size,
                              hipStream_t stream)
{
    const float* h  = (const float*)d_in[0];
    const float* W  = (const float*)d_in[1];
    const float* Wb = (const float*)d_in[2];
    const float* aw = (const float*)d_in[3];
    const float* ab = (const float*)d_in[4];
    const int*   ei = (const int*)d_in[5];

    // ws layout: Wh[N*64] f32 | s_src[N] | s_tgt[N] | deg[N] u32 | row[N+1] u32
    //          | cursor[N] u32 | psum[512] | poff[512] | bin_src[E] | bin_a[E]
    //          | gmax u32 | gsum f32
    float* ws      = (float*)d_ws;
    float* Wh      = ws;
    float* s_src   = Wh + (size_t)N_NODES * OUT_DIM;
    float* s_tgt   = s_src + N_NODES;
    unsigned* deg    = (unsigned*)(s_tgt + N_NODES);
    unsigned* row    = deg + N_NODES;
    unsigned* cursor = row + N_NODES + 1;
    unsigned* psum   = cursor + N_NODES;
    unsigned* poff   = psum + 512;
    int*      bin_src = (int*)(poff + 512);
    float*    bin_a   = (float*)(bin_src + N_EDGES);
    unsigned* gmax    = (unsigned*)(bin_a + N_EDGES);
    float*    gsum    = (float*)(gmax + 1);

    float* out = (float*)d_out;

    hipMemsetAsync((void*)deg, 0, N_NODES * sizeof(unsigned), stream);
    hipMemsetAsync((void*)gmax, 0, 8, stream);  // fmap-uint 0 == -inf; sum = 0

    k1_gemm<<<N_NODES / 32, 256, 0, stream>>>(h, W, Wb, aw, Wh, s_src, s_tgt);
    k2_maxhist<<<1024, 256, 0, stream>>>(ei, s_src, s_tgt, ab, deg, gmax);
    k_scan1<<<SCAN_BLOCKS, 256, 0, stream>>>(deg, psum);
    k_scan2<<<1, 512, 0, stream>>>(psum, poff);
    k_scan3<<<SCAN_BLOCKS, 256, 0, stream>>>(deg, poff, row, cursor);
    k3_expfill<<<1024, 256, 0, stream>>>(ei, s_src, s_tgt, ab, gmax, gsum,
                                         cursor, bin_src, bin_a);
    k_gather<<<(N_NODES + 3) / 4, 256, 0, stream>>>(row, bin_src, bin_a, gsum,
                                                    Wh, out);
}